// Round 1
// baseline (5294.852 us; speedup 1.0000x reference)
//
#include <hip/hip_runtime.h>

// MyLSTM_GCN: B=4096, T=128, H=156, L=2, O=12
// Strategy: 256 independent workgroups (1/CU), each owns 16 batch samples and
// runs the full 128-step recurrence with states in LDS. All matmuls via
// mfma_f32_16x16x32_f16 (M=16 samples, N=features, K=features), weights
// pre-converted to padded f16 [160][160] in workspace. Output projection
// accumulated directly into d_out (flat-view reshape math folded in).

#define HH 156
#define HP 160
#define TT 128
#define OO 12
#define LDSS 168          // LDS row stride in f16 (336 B: 16B-aligned, ~2-way banks)
#define MATSZ (HP*HP)     // 25600 f16 per padded matrix

typedef _Float16 f16x8 __attribute__((ext_vector_type(8)));
typedef float    f32x4 __attribute__((ext_vector_type(4)));

__device__ __forceinline__ float sigm(float v) { return 1.0f / (1.0f + __expf(-v)); }
__device__ __forceinline__ float tanh_(float v) { return 2.0f / (1.0f + __expf(-2.0f * v)) - 1.0f; }

// ---------------------------------------------------------------------------
// Phase 0: transcode 17 weight matrices (adj + 8x{Wx,Wh}) to padded f16
// [160][160] row-major (row = output feature n, col = input feature k),
// and build combined biases bias_comb[j][g][160] = b*x + b*h (fp32).
// mat id: 0 = adj; 1 + (j*4+g)*2 + s  (s=0: Wx, s=1: Wh), gate order i,f,o,c.
// ---------------------------------------------------------------------------
__global__ __launch_bounds__(256) void prep_kernel(
    const float* __restrict__ adj,
    const float* __restrict__ Wix, const float* __restrict__ Wih,
    const float* __restrict__ Wfx, const float* __restrict__ Wfh,
    const float* __restrict__ Wcx, const float* __restrict__ Wch,
    const float* __restrict__ Wox, const float* __restrict__ Woh,
    const float* __restrict__ bix, const float* __restrict__ bih,
    const float* __restrict__ bfx, const float* __restrict__ bfh,
    const float* __restrict__ bcx, const float* __restrict__ bch,
    const float* __restrict__ box_, const float* __restrict__ boh,
    _Float16* __restrict__ wmats, float* __restrict__ bias_comb)
{
    int idx = blockIdx.x * 256 + threadIdx.x;
    if (idx < 17 * MATSZ) {
        int mat = idx / MATSZ;
        int r   = idx % MATSZ;
        int nrow = r / HP, k = r % HP;
        float v = 0.f;
        if (nrow < HH && k < HH) {
            if (mat == 0) {
                v = adj[nrow * HH + k];
            } else {
                int m2 = mat - 1;
                int s  = m2 & 1;
                int jg = m2 >> 1;
                int j  = jg >> 2;
                int g  = jg & 3;
                const float* W;
                if (s == 0) W = (g == 0) ? Wix : (g == 1) ? Wfx : (g == 2) ? Wox : Wcx;
                else        W = (g == 0) ? Wih : (g == 1) ? Wfh : (g == 2) ? Woh : Wch;
                v = W[j * (HH * HH) + nrow * HH + k];
            }
        }
        wmats[idx] = (_Float16)v;
    } else if (idx < 17 * MATSZ + 2 * 4 * HP) {
        int r = idx - 17 * MATSZ;
        int j = r / (4 * HP);
        int g = (r % (4 * HP)) / HP;
        int nn = r % HP;
        float v = 0.f;
        if (nn < HH) {
            const float* Bx = (g == 0) ? bix : (g == 1) ? bfx : (g == 2) ? box_ : bcx;
            const float* Bh = (g == 0) ? bih : (g == 1) ? bfh : (g == 2) ? boh : bch;
            v = Bx[j * HH + nn] + Bh[j * HH + nn];
        }
        bias_comb[r] = v;
    }
}

// ---------------------------------------------------------------------------
// Phase 0b: init the projection output region with b_out (accumulated into
// by the main kernel). Layout: out[b*1872 + i*12 + o], o = idx % 12.
// ---------------------------------------------------------------------------
__global__ __launch_bounds__(256) void init_out_kernel(
    float* __restrict__ out, const float* __restrict__ b_out, int total)
{
    int idx = blockIdx.x * 256 + threadIdx.x;
    if (idx < total) out[idx] = b_out[idx % OO];
}

// ---------------------------------------------------------------------------
// Main recurrent kernel: grid = 256 WGs x 640 threads (10 waves).
// Wave w owns feature N-tile n = w*16 + (lane&15) in every matmul phase.
// MFMA 16x16x32 f16: A[m=lane&15][k=quad*8+j] from LDS, B[k][n] read as 8
// contiguous f16 from row n of the padded [160][160] global weight matrix.
// C/D: col = lane&15 (feature), row m = quad*4 + reg (sample).
// ---------------------------------------------------------------------------
__global__ __launch_bounds__(640) void lstm_main(
    const float* __restrict__ x,
    const _Float16* __restrict__ wmats,
    const float* __restrict__ bias_comb,
    const float* __restrict__ w_out,
    const float* __restrict__ gcn_w1,
    const float* __restrict__ gcn_w2,
    float* __restrict__ out)
{
    __shared__ __align__(16) _Float16 st_c[2][16][LDSS];
    __shared__ __align__(16) _Float16 st_h[2][16][LDSS];
    __shared__ __align__(16) _Float16 xb[16][LDSS];
    __shared__ __align__(16) _Float16 tmp[64][LDSS];
    __shared__ float wout_s[OO][TT];
    __shared__ float bias_s[2][4][HP];

    const int tid  = threadIdx.x;
    const int wave = tid >> 6;
    const int lane = tid & 63;
    const int lcol = lane & 15;
    const int quad = lane >> 4;
    const int b0   = blockIdx.x << 4;       // 16 samples per WG
    const int n    = (wave << 4) + lcol;    // this wave's feature column

    // init LDS: zero states, stage W_out and biases
    for (int e = tid; e < 2 * 16 * LDSS; e += 640) {
        (&st_c[0][0][0])[e] = (_Float16)0.f;
        (&st_h[0][0][0])[e] = (_Float16)0.f;
    }
    for (int e = tid; e < OO * TT; e += 640) (&wout_s[0][0])[e] = w_out[e];
    for (int e = tid; e < 2 * 4 * HP; e += 640) (&bias_s[0][0][0])[e] = bias_comb[e];
    const float gw1_0 = gcn_w1[0], gw1_1 = gcn_w1[1];
    const float gw2_0 = gcn_w2[0], gw2_1 = gcn_w2[1];
    __syncthreads();

    for (int t = 0; t < TT; ++t) {
        // ---- stage x_t (fp32 global -> f16 LDS), pad cols zeroed ----
        for (int e = tid; e < 16 * HP; e += 640) {
            int m = e / HP, f = e % HP;
            float v = (f < HH) ? x[((size_t)(b0 + m) * TT + t) * HH + f] : 0.f;
            xb[m][f] = (_Float16)v;
        }
        __syncthreads();   // x ready; prev-step state writes + proj reads done

        if (t > 0) {
            // B-frags of adj (mat 0), reused across all 4 state blocks
            f16x8 badj[5];
            #pragma unroll
            for (int kk = 0; kk < 5; ++kk)
                badj[kk] = *(const f16x8*)&wmats[(size_t)n * HP + kk * 32 + quad * 8];

            // ---- GCN stage 1: tmp = relu(w1 * (state @ adj^T)) ----
            #pragma unroll
            for (int mt = 0; mt < 4; ++mt) {   // c0, h0, c1, h1
                const _Float16* Ab = (mt == 0) ? &st_c[0][0][0] : (mt == 1) ? &st_h[0][0][0]
                                   : (mt == 2) ? &st_c[1][0][0] : &st_h[1][0][0];
                f32x4 acc = {0.f, 0.f, 0.f, 0.f};
                #pragma unroll
                for (int kk = 0; kk < 5; ++kk) {
                    f16x8 a = *(const f16x8*)&Ab[lcol * LDSS + kk * 32 + quad * 8];
                    acc = __builtin_amdgcn_mfma_f32_16x16x32_f16(a, badj[kk], acc, 0, 0, 0);
                }
                float w1 = (mt < 2) ? gw1_0 : gw1_1;
                #pragma unroll
                for (int r = 0; r < 4; ++r) {
                    float v = acc[r] * w1;
                    tmp[(mt << 4) + (quad << 2) + r][n] = (_Float16)(v > 0.f ? v : 0.f);
                }
            }
            __syncthreads();

            // ---- GCN stage 2: state = sigmoid(w2 * (tmp @ adj^T)) ----
            #pragma unroll
            for (int mt = 0; mt < 4; ++mt) {
                f32x4 acc = {0.f, 0.f, 0.f, 0.f};
                #pragma unroll
                for (int kk = 0; kk < 5; ++kk) {
                    f16x8 a = *(const f16x8*)&tmp[(mt << 4) + lcol][kk * 32 + quad * 8];
                    acc = __builtin_amdgcn_mfma_f32_16x16x32_f16(a, badj[kk], acc, 0, 0, 0);
                }
                float w2 = (mt < 2) ? gw2_0 : gw2_1;
                _Float16 (*dst)[LDSS] = (mt == 0) ? st_c[0] : (mt == 1) ? st_h[0]
                                      : (mt == 2) ? st_c[1] : st_h[1];
                #pragma unroll
                for (int r = 0; r < 4; ++r) {
                    float v = sigm(acc[r] * w2);
                    dst[(quad << 2) + r][n] = (_Float16)v;
                }
            }
            __syncthreads();
        }

        // ---- gates: preact = x_t @ Wx^T + h @ Wh^T  (both layers, 4 gates) ----
        f16x8 ax[5], ah[2][5];
        #pragma unroll
        for (int kk = 0; kk < 5; ++kk) {
            ax[kk]    = *(const f16x8*)&xb[lcol][kk * 32 + quad * 8];
            ah[0][kk] = *(const f16x8*)&st_h[0][lcol][kk * 32 + quad * 8];
            ah[1][kk] = *(const f16x8*)&st_h[1][lcol][kk * 32 + quad * 8];
        }
        f32x4 acc[2][4];
        #pragma unroll
        for (int j = 0; j < 2; ++j) {
            #pragma unroll
            for (int g = 0; g < 4; ++g) {
                f32x4 a_ = {0.f, 0.f, 0.f, 0.f};
                const _Float16* Wx = wmats + (size_t)(1 + ((j << 2) + g) * 2) * MATSZ;
                const _Float16* Wh = Wx + MATSZ;
                #pragma unroll
                for (int kk = 0; kk < 5; ++kk) {
                    f16x8 b = *(const f16x8*)&Wx[(size_t)n * HP + kk * 32 + quad * 8];
                    a_ = __builtin_amdgcn_mfma_f32_16x16x32_f16(ax[kk], b, a_, 0, 0, 0);
                }
                #pragma unroll
                for (int kk = 0; kk < 5; ++kk) {
                    f16x8 b = *(const f16x8*)&Wh[(size_t)n * HP + kk * 32 + quad * 8];
                    a_ = __builtin_amdgcn_mfma_f32_16x16x32_f16(ah[j][kk], b, a_, 0, 0, 0);
                }
                acc[j][g] = a_;
            }
        }
        __syncthreads();   // all st_h A-reads done -> safe to overwrite states

        // ---- elementwise LSTM update (each wave owns its feature column n) ----
        #pragma unroll
        for (int j = 0; j < 2; ++j) {
            float bi = bias_s[j][0][n], bf = bias_s[j][1][n],
                  bo = bias_s[j][2][n], bg = bias_s[j][3][n];
            #pragma unroll
            for (int r = 0; r < 4; ++r) {
                int m = (quad << 2) + r;
                float i_ = sigm(acc[j][0][r] + bi);
                float f_ = sigm(acc[j][1][r] + bf);
                float o_ = sigm(acc[j][2][r] + bo);
                float g_ = tanh_(acc[j][3][r] + bg);
                float c_old = (float)st_c[j][m][n];    // post-GCN c
                float c_new = f_ * c_old + i_ * g_;
                float h_new = o_ * tanh_(c_new);
                st_c[j][m][n] = (_Float16)c_new;
                st_h[j][m][n] = (_Float16)h_new;
            }
        }
        __syncthreads();   // h1 complete for projection

        // ---- projection accumulate: out[b, i*12+o] += y * W_out[o, t'] ----
        // y_flat[b, t*156+f] = h1[b,f]; k = t*156+f -> i = k>>7, t' = k&127.
        if (tid < 192) {
            const int m = tid & 15;
            const int o = tid >> 4;
            const int kbase = t * HH;
            int icur = kbase >> 7;
            float s = 0.f;
            float* obase = out + (size_t)(b0 + m) * (HH * OO) + o;
            for (int f = 0; f < HH; ++f) {
                int k = kbase + f;
                int i = k >> 7;
                if (i != icur) { obase[icur * OO] += s; s = 0.f; icur = i; }
                s += (float)st_h[1][m][f] * wout_s[o][k & (TT - 1)];
            }
            obase[icur * OO] += s;
        }
    }

    __syncthreads();
    // ---- epilogue: h_n, c_n (fp32) ----
    float* hn = out + (size_t)4096 * HH * OO;
    float* cn = hn + (size_t)2 * 4096 * HH;
    for (int e = tid; e < 2 * 16 * HH; e += 640) {
        int j  = e / (16 * HH);
        int r2 = e % (16 * HH);
        int m  = r2 / HH;
        int f  = r2 % HH;
        size_t off = ((size_t)j * 4096 + b0 + m) * HH + f;
        hn[off] = (float)st_h[j][m][f];
        cn[off] = (float)st_c[j][m][f];
    }
}

// ---------------------------------------------------------------------------
extern "C" void kernel_launch(void* const* d_in, const int* in_sizes, int n_in,
                              void* d_out, int out_size, void* d_ws, size_t ws_size,
                              hipStream_t stream) {
    const float* x    = (const float*)d_in[0];
    const float* adj  = (const float*)d_in[1];
    const float* Wix  = (const float*)d_in[2];  const float* bix = (const float*)d_in[3];
    const float* Wih  = (const float*)d_in[4];  const float* bih = (const float*)d_in[5];
    const float* Wfx  = (const float*)d_in[6];  const float* bfx = (const float*)d_in[7];
    const float* Wfh  = (const float*)d_in[8];  const float* bfh = (const float*)d_in[9];
    const float* Wcx  = (const float*)d_in[10]; const float* bcx = (const float*)d_in[11];
    const float* Wch  = (const float*)d_in[12]; const float* bch = (const float*)d_in[13];
    const float* Wox  = (const float*)d_in[14]; const float* box_ = (const float*)d_in[15];
    const float* Woh  = (const float*)d_in[16]; const float* boh = (const float*)d_in[17];
    const float* gw1  = (const float*)d_in[18];
    const float* gw2  = (const float*)d_in[19];
    const float* Wout = (const float*)d_in[20];
    const float* bout = (const float*)d_in[21];

    _Float16* wmats   = (_Float16*)d_ws;
    float* bias_comb  = (float*)((char*)d_ws + (size_t)17 * MATSZ * sizeof(_Float16));
    float* out        = (float*)d_out;

    // phase 0: weight transcode + combined biases (17*25600 + 1280 threads)
    prep_kernel<<<(17 * MATSZ + 2 * 4 * HP + 255) / 256, 256, 0, stream>>>(
        adj, Wix, Wih, Wfx, Wfh, Wcx, Wch, Wox, Woh,
        bix, bih, bfx, bfh, bcx, bch, box_, boh, wmats, bias_comb);

    // phase 0b: init projection output with b_out
    const int proj_total = 4096 * HH * OO;
    init_out_kernel<<<(proj_total + 255) / 256, 256, 0, stream>>>(out, bout, proj_total);

    // main recurrent kernel: 256 WGs x 640 threads
    lstm_main<<<256, 640, 0, stream>>>(x, wmats, bias_comb, Wout, gw1, gw2, out);
}

// Round 2
// 5267.595 us; speedup vs baseline: 1.0052x; 1.0052x over previous
//
#include <hip/hip_runtime.h>

// MyLSTM_GCN: B=4096, T=128, H=156, L=2, O=12
// R2: latency-focused restructure.
//  - projection -> MFMA on waves 0-2 for step t-1, overlapped with x-staging (waves 3-9)
//  - gate weights: 3-deep register prefetch pipeline (5 frags = 1 matrix per chunk)
//  - adj B-frags prefetched at step top; wout_s padded to kill 12-way conflicts
//  - __launch_bounds__(640,3): VGPR cap ~170 (10-wave block needs >=3 waves/SIMD)

#define HH 156
#define HP 160
#define TT 128
#define OO 12
#define LDSS 168          // LDS row stride in f16
#define MATSZ (HP*HP)     // 25600 f16 per padded matrix

typedef _Float16 f16x8 __attribute__((ext_vector_type(8)));
typedef _Float16 f16x4 __attribute__((ext_vector_type(4)));
typedef float    f32x4 __attribute__((ext_vector_type(4)));

__device__ __forceinline__ float sigm(float v) { return 1.0f / (1.0f + __expf(-v)); }
__device__ __forceinline__ float tanh_(float v) { return 2.0f / (1.0f + __expf(-2.0f * v)) - 1.0f; }

// ---------------------------------------------------------------------------
// Phase 0: transcode 17 weight matrices (adj + 8x{Wx,Wh}) to padded f16
// [160][160] row-major (row = output feature n, col = input feature k),
// and combined biases bias_comb[j][g][160] = bx + bh (fp32).
// mat id: 0 = adj; 1 + (j*4+g)*2 + s  (s=0: Wx, s=1: Wh), gate order i,f,o,c.
// ---------------------------------------------------------------------------
__global__ __launch_bounds__(256) void prep_kernel(
    const float* __restrict__ adj,
    const float* __restrict__ Wix, const float* __restrict__ Wih,
    const float* __restrict__ Wfx, const float* __restrict__ Wfh,
    const float* __restrict__ Wcx, const float* __restrict__ Wch,
    const float* __restrict__ Wox, const float* __restrict__ Woh,
    const float* __restrict__ bix, const float* __restrict__ bih,
    const float* __restrict__ bfx, const float* __restrict__ bfh,
    const float* __restrict__ bcx, const float* __restrict__ bch,
    const float* __restrict__ box_, const float* __restrict__ boh,
    _Float16* __restrict__ wmats, float* __restrict__ bias_comb)
{
    int idx = blockIdx.x * 256 + threadIdx.x;
    if (idx < 17 * MATSZ) {
        int mat = idx / MATSZ;
        int r   = idx % MATSZ;
        int nrow = r / HP, k = r % HP;
        float v = 0.f;
        if (nrow < HH && k < HH) {
            if (mat == 0) {
                v = adj[nrow * HH + k];
            } else {
                int m2 = mat - 1;
                int s  = m2 & 1;
                int jg = m2 >> 1;
                int j  = jg >> 2;
                int g  = jg & 3;
                const float* W;
                if (s == 0) W = (g == 0) ? Wix : (g == 1) ? Wfx : (g == 2) ? Wox : Wcx;
                else        W = (g == 0) ? Wih : (g == 1) ? Wfh : (g == 2) ? Woh : Wch;
                v = W[j * (HH * HH) + nrow * HH + k];
            }
        }
        wmats[idx] = (_Float16)v;
    } else if (idx < 17 * MATSZ + 2 * 4 * HP) {
        int r = idx - 17 * MATSZ;
        int j = r / (4 * HP);
        int g = (r % (4 * HP)) / HP;
        int nn = r % HP;
        float v = 0.f;
        if (nn < HH) {
            const float* Bx = (g == 0) ? bix : (g == 1) ? bfx : (g == 2) ? box_ : bcx;
            const float* Bh = (g == 0) ? bih : (g == 1) ? bfh : (g == 2) ? boh : bch;
            v = Bx[j * HH + nn] + Bh[j * HH + nn];
        }
        bias_comb[r] = v;
    }
}

__global__ __launch_bounds__(256) void init_out_kernel(
    float* __restrict__ out, const float* __restrict__ b_out, int total)
{
    int idx = blockIdx.x * 256 + threadIdx.x;
    if (idx < total) out[idx] = b_out[idx % OO];
}

// load 5 B-fragments (one padded 160x160 matrix's worth for column n) to regs
__device__ __forceinline__ void load5(f16x8* dst, const _Float16* mat, int n, int qo) {
    #pragma unroll
    for (int kk = 0; kk < 5; ++kk)
        dst[kk] = *(const f16x8*)&mat[(size_t)n * HP + kk * 32 + qo];
}

// ---------------------------------------------------------------------------
// Main recurrent kernel: 256 WGs x 640 threads (10 waves, 1 WG/CU).
// Wave w owns feature columns n = w*16 + (lane&15).
// ---------------------------------------------------------------------------
__global__ __launch_bounds__(640, 3) void lstm_main(
    const float* __restrict__ x,
    const _Float16* __restrict__ wmats,
    const float* __restrict__ bias_comb,
    const float* __restrict__ w_out,
    const float* __restrict__ gcn_w1,
    const float* __restrict__ gcn_w2,
    float* __restrict__ out)
{
    __shared__ __align__(16) _Float16 st_c[2][16][LDSS];
    __shared__ __align__(16) _Float16 st_h[2][16][LDSS];
    __shared__ __align__(16) _Float16 xb[16][LDSS];
    __shared__ __align__(16) _Float16 tmp[64][LDSS];
    __shared__ float wout_s[OO][TT + 1];   // +1 pad: kills 12-way bank conflicts
    __shared__ float bias_s[2][4][HP];

    const int tid  = threadIdx.x;
    const int wave = tid >> 6;
    const int lane = tid & 63;
    const int lcol = lane & 15;
    const int quad = lane >> 4;
    const int qoff = quad << 3;
    const int b0   = blockIdx.x << 4;
    const int n    = (wave << 4) + lcol;

    for (int e = tid; e < 2 * 16 * LDSS; e += 640) {
        (&st_c[0][0][0])[e] = (_Float16)0.f;
        (&st_h[0][0][0])[e] = (_Float16)0.f;
    }
    for (int e = tid; e < OO * TT; e += 640) wout_s[e / TT][e % TT] = w_out[e];
    for (int e = tid; e < 2 * 4 * HP; e += 640) (&bias_s[0][0][0])[e] = bias_comb[e];
    const float gw1_0 = gcn_w1[0], gw1_1 = gcn_w1[1];
    const float gw2_0 = gcn_w2[0], gw2_1 = gcn_w2[1];
    __syncthreads();

    // proj(tp, plane): out[b, i, o] += sum_f h1[b,f] * Wout[o, tp*156+f - i*128]
    // done as one 16x16xK MFMA per plane (i = ((tp*156)>>7) + plane).
    auto proj = [&](int tp, int plane) {
        const int i = ((tp * HH) >> 7) + plane;
        const int s = i * TT - tp * HH;       // t' = f - s
        if (s >= HH) return;                  // empty third plane
        const int lc = (lcol < OO) ? lcol : 0;
        f16x8 bf[5];
        #pragma unroll
        for (int kk = 0; kk < 5; ++kk) {
            f16x8 b;
            #pragma unroll
            for (int e = 0; e < 8; ++e) {
                int f  = kk * 32 + qoff + e;
                int tq = f - s;
                bool ok = (lcol < OO) && (tq >= 0) && (tq < TT) && (f < HH);
                int tqc = tq < 0 ? 0 : (tq > TT - 1 ? TT - 1 : tq);
                b[e] = (_Float16)(ok ? wout_s[lc][tqc] : 0.f);
            }
            bf[kk] = b;
        }
        f32x4 a_ = {0.f, 0.f, 0.f, 0.f};
        #pragma unroll
        for (int kk = 0; kk < 5; ++kk) {
            f16x8 a = *(const f16x8*)&st_h[1][lcol][kk * 32 + qoff];
            a_ = __builtin_amdgcn_mfma_f32_16x16x32_f16(a, bf[kk], a_, 0, 0, 0);
        }
        if (lcol < OO) {
            #pragma unroll
            for (int r = 0; r < 4; ++r) {
                float* p = out + (size_t)(b0 + (quad << 2) + r) * (HH * OO) + i * OO + lcol;
                *p += a_[r];
            }
        }
    };

    f16x8 wb[3][5];   // 3-deep gate-weight prefetch pipeline
    f16x8 badj[5];

    for (int t = 0; t < TT; ++t) {
        // ---- phase A: issue prefetches first, then proj(t-1) || x-stage ----
        load5(wb[0], wmats + (size_t)1 * MATSZ, n, qoff);
        load5(wb[1], wmats + (size_t)2 * MATSZ, n, qoff);
        load5(wb[2], wmats + (size_t)3 * MATSZ, n, qoff);
        if (t > 0) load5(badj, wmats, n, qoff);

        if (wave < 3) {
            if (t > 0) proj(t - 1, wave);
        } else {
            for (int e = tid - 192; e < 640; e += 448) {
                int m = e / 40, q = e % 40, f = q << 2;
                float4 v = make_float4(0.f, 0.f, 0.f, 0.f);
                if (f + 4 <= HH) v = *(const float4*)&x[((size_t)(b0 + m) * TT + t) * HH + f];
                f16x4 h4 = {(_Float16)v.x, (_Float16)v.y, (_Float16)v.z, (_Float16)v.w};
                *(f16x4*)&xb[m][f] = h4;
            }
        }
        __syncthreads();   // B1: xb ready, proj done, states stable

        if (t > 0) {
            // ---- GCN stage 1: tmp = relu(w1 * (state @ adj^T)) ----
            #pragma unroll
            for (int mt = 0; mt < 4; ++mt) {   // c0, h0, c1, h1
                const _Float16* Ab = (mt == 0) ? &st_c[0][0][0] : (mt == 1) ? &st_h[0][0][0]
                                   : (mt == 2) ? &st_c[1][0][0] : &st_h[1][0][0];
                f32x4 acc = {0.f, 0.f, 0.f, 0.f};
                #pragma unroll
                for (int kk = 0; kk < 5; ++kk) {
                    f16x8 a = *(const f16x8*)&Ab[lcol * LDSS + kk * 32 + qoff];
                    acc = __builtin_amdgcn_mfma_f32_16x16x32_f16(a, badj[kk], acc, 0, 0, 0);
                }
                float w1 = (mt < 2) ? gw1_0 : gw1_1;
                #pragma unroll
                for (int r = 0; r < 4; ++r) {
                    float v = acc[r] * w1;
                    tmp[(mt << 4) + (quad << 2) + r][n] = (_Float16)(v > 0.f ? v : 0.f);
                }
            }
            __syncthreads();   // B2

            // ---- GCN stage 2: state = sigmoid(w2 * (tmp @ adj^T)) ----
            #pragma unroll
            for (int mt = 0; mt < 4; ++mt) {
                f32x4 acc = {0.f, 0.f, 0.f, 0.f};
                #pragma unroll
                for (int kk = 0; kk < 5; ++kk) {
                    f16x8 a = *(const f16x8*)&tmp[(mt << 4) + lcol][kk * 32 + qoff];
                    acc = __builtin_amdgcn_mfma_f32_16x16x32_f16(a, badj[kk], acc, 0, 0, 0);
                }
                float w2 = (mt < 2) ? gw2_0 : gw2_1;
                _Float16 (*dst)[LDSS] = (mt == 0) ? st_c[0] : (mt == 1) ? st_h[0]
                                      : (mt == 2) ? st_c[1] : st_h[1];
                #pragma unroll
                for (int r = 0; r < 4; ++r)
                    dst[(quad << 2) + r][n] = (_Float16)sigm(acc[r] * w2);
            }
            __syncthreads();   // B3
        }

        // ---- gates: 16 matrices streamed through 3-buffer pipeline ----
        f32x4 acc[8];
        #pragma unroll
        for (int jg = 0; jg < 8; ++jg) acc[jg] = (f32x4){0.f, 0.f, 0.f, 0.f};
        #pragma unroll
        for (int mi = 1; mi <= 16; ++mi) {
            const int s_ = (mi - 1) & 1;       // 0: Wx (A=xb), 1: Wh (A=st_h[j])
            const int jg = (mi - 1) >> 1;
            const int j  = jg >> 2;
            const _Float16* A = s_ ? &st_h[j][lcol][0] : &xb[lcol][0];
            #pragma unroll
            for (int kk = 0; kk < 5; ++kk) {
                f16x8 a = *(const f16x8*)&A[kk * 32 + qoff];
                acc[jg] = __builtin_amdgcn_mfma_f32_16x16x32_f16(a, wb[(mi - 1) % 3][kk], acc[jg], 0, 0, 0);
            }
            if (mi + 3 <= 16)
                load5(wb[(mi - 1) % 3], wmats + (size_t)(mi + 3) * MATSZ, n, qoff);
        }
        __syncthreads();   // B4: all st_h/xb A-reads done

        // ---- elementwise LSTM update ----
        #pragma unroll
        for (int j = 0; j < 2; ++j) {
            float bi = bias_s[j][0][n], bf = bias_s[j][1][n],
                  bo = bias_s[j][2][n], bg = bias_s[j][3][n];
            #pragma unroll
            for (int r = 0; r < 4; ++r) {
                int m = (quad << 2) + r;
                float i_ = sigm(acc[j * 4 + 0][r] + bi);
                float f_ = sigm(acc[j * 4 + 1][r] + bf);
                float o_ = sigm(acc[j * 4 + 2][r] + bo);
                float g_ = tanh_(acc[j * 4 + 3][r] + bg);
                float c_old = (float)st_c[j][m][n];
                float c_new = f_ * c_old + i_ * g_;
                float h_new = o_ * tanh_(c_new);
                st_c[j][m][n] = (_Float16)c_new;
                st_h[j][m][n] = (_Float16)h_new;
            }
        }
        __syncthreads();   // B5: updates visible to next phase A / GCN
    }

    // final projection for t=127 + epilogue
    if (wave < 3) proj(TT - 1, wave);

    float* hn = out + (size_t)4096 * HH * OO;
    float* cn = hn + (size_t)2 * 4096 * HH;
    for (int e = tid; e < 2 * 16 * HH; e += 640) {
        int j  = e / (16 * HH);
        int r2 = e % (16 * HH);
        int m  = r2 / HH;
        int f  = r2 % HH;
        size_t off = ((size_t)j * 4096 + b0 + m) * HH + f;
        hn[off] = (float)st_h[j][m][f];
        cn[off] = (float)st_c[j][m][f];
    }
}

// ---------------------------------------------------------------------------
extern "C" void kernel_launch(void* const* d_in, const int* in_sizes, int n_in,
                              void* d_out, int out_size, void* d_ws, size_t ws_size,
                              hipStream_t stream) {
    const float* x    = (const float*)d_in[0];
    const float* adj  = (const float*)d_in[1];
    const float* Wix  = (const float*)d_in[2];  const float* bix = (const float*)d_in[3];
    const float* Wih  = (const float*)d_in[4];  const float* bih = (const float*)d_in[5];
    const float* Wfx  = (const float*)d_in[6];  const float* bfx = (const float*)d_in[7];
    const float* Wfh  = (const float*)d_in[8];  const float* bfh = (const float*)d_in[9];
    const float* Wcx  = (const float*)d_in[10]; const float* bcx = (const float*)d_in[11];
    const float* Wch  = (const float*)d_in[12]; const float* bch = (const float*)d_in[13];
    const float* Wox  = (const float*)d_in[14]; const float* box_ = (const float*)d_in[15];
    const float* Woh  = (const float*)d_in[16]; const float* boh = (const float*)d_in[17];
    const float* gw1  = (const float*)d_in[18];
    const float* gw2  = (const float*)d_in[19];
    const float* Wout = (const float*)d_in[20];
    const float* bout = (const float*)d_in[21];

    _Float16* wmats   = (_Float16*)d_ws;
    float* bias_comb  = (float*)((char*)d_ws + (size_t)17 * MATSZ * sizeof(_Float16));
    float* out        = (float*)d_out;

    prep_kernel<<<(17 * MATSZ + 2 * 4 * HP + 255) / 256, 256, 0, stream>>>(
        adj, Wix, Wih, Wfx, Wfh, Wcx, Wch, Wox, Woh,
        bix, bih, bfx, bfh, bcx, bch, box_, boh, wmats, bias_comb);

    const int proj_total = 4096 * HH * OO;
    init_out_kernel<<<(proj_total + 255) / 256, 256, 0, stream>>>(out, bout, proj_total);

    lstm_main<<<256, 640, 0, stream>>>(x, wmats, bias_comb, Wout, gw1, gw2, out);
}